// Round 1
// baseline (754.194 us; speedup 1.0000x reference)
//
#include <hip/hip_runtime.h>
#include <math.h>

// Problem constants (from reference setup_inputs): B=4,H=16,S=8192,D=128
#define BH   64      // B*H
#define SEQ  8192
#define DIM  128
#define NB   16      // num_blocks = S / BLOCK_SIZE
#define BS   512     // BLOCK_SIZE
#define QPT  4       // queries per thread in score kernel

// ---------------------------------------------------------------------------
// Kernel 1: k_mean[bh][nb][d] = mean over BS rows of k, double accumulation.
// Grid: BH*NB = 1024 blocks, 256 threads. Coalesced: wave covers 2 rows of
// 512B contiguous float4 reads per instruction.
// ---------------------------------------------------------------------------
__global__ __launch_bounds__(256) void kmean_kernel(const float* __restrict__ k,
                                                    float* __restrict__ kmean) {
  int blk = blockIdx.x;            // 0..BH*NB-1
  int bh  = blk >> 4;
  int nb  = blk & 15;
  const float4* base = (const float4*)(k + ((size_t)bh * SEQ + (size_t)nb * BS) * DIM);
  int t  = threadIdx.x;
  int c4 = t & 31;                 // column group (float4 index within row)
  int r0 = t >> 5;                 // 0..7
  double a0 = 0, a1 = 0, a2 = 0, a3 = 0;
  for (int r = r0; r < BS; r += 8) {
    float4 v = base[r * 32 + c4];
    a0 += (double)v.x; a1 += (double)v.y; a2 += (double)v.z; a3 += (double)v.w;
  }
  __shared__ double red[8][32][4];
  red[r0][c4][0] = a0; red[r0][c4][1] = a1;
  red[r0][c4][2] = a2; red[r0][c4][3] = a3;
  __syncthreads();
  if (r0 == 0) {
    double s0 = 0, s1 = 0, s2 = 0, s3 = 0;
#pragma unroll
    for (int r = 0; r < 8; ++r) {
      s0 += red[r][c4][0]; s1 += red[r][c4][1];
      s2 += red[r][c4][2]; s3 += red[r][c4][3];
    }
    const double inv = 1.0 / (double)BS;    // exact power of two
    float4 o;
    o.x = (float)(s0 * inv); o.y = (float)(s1 * inv);
    o.z = (float)(s2 * inv); o.w = (float)(s3 * inv);
    ((float4*)kmean)[((size_t)bh * NB + nb) * 32 + c4] = o;
  }
}

// ---------------------------------------------------------------------------
// Kernel 2: scores + causal mask + stable top-4.
// Grid: BH*SEQ/(256*QPT) = 512 blocks, 256 threads; block handles 1024
// consecutive queries within one bh. k_mean[bh] staged in LDS (8 KB),
// read as wave-uniform broadcast (conflict-free). Scores accumulated in
// double for max fidelity to the fp32 reference ranking. Causal skip:
// block-uniform `n < nn` guard on a fully-unrolled loop keeps register
// arrays statically indexed while saving ~47% of the FMA work.
// ---------------------------------------------------------------------------
__global__ __launch_bounds__(256) void score_topk_kernel(const float* __restrict__ q,
                                                         const float* __restrict__ kmean,
                                                         int* __restrict__ out) {
  __shared__ float4 kk[NB * 32];        // 16 rows x 128 floats = 8 KB
  int blk  = blockIdx.x;                // 0..511
  int base = blk * 1024;                // global query index base (bh*SEQ + s)
  int bh   = base >> 13;                // base / SEQ
  int t    = threadIdx.x;

  const float4* ksrc = (const float4*)(kmean + (size_t)bh * NB * DIM);
  for (int i = t; i < NB * 32; i += 256) kk[i] = ksrc[i];
  __syncthreads();

  int s_base = base & (SEQ - 1);
  int nn = ((s_base + 1023) >> 9) + 1;  // #blocks any query in this WG can see

  double sc[QPT][NB];
#pragma unroll
  for (int j = 0; j < QPT; ++j)
#pragma unroll
    for (int n = 0; n < NB; ++n) sc[j][n] = 0.0;

  const float4* qbase = (const float4*)(q + (size_t)base * DIM);

  for (int d4 = 0; d4 < 32; ++d4) {
    double qd[QPT][4];
#pragma unroll
    for (int j = 0; j < QPT; ++j) {
      float4 v = qbase[(size_t)(t + j * 256) * 32 + d4];
      qd[j][0] = (double)v.x; qd[j][1] = (double)v.y;
      qd[j][2] = (double)v.z; qd[j][3] = (double)v.w;
    }
#pragma unroll
    for (int n = 0; n < NB; ++n) {
      if (n < nn) {                     // block-uniform scalar branch
        float4 kv = kk[n * 32 + d4];
        double kx = (double)kv.x, ky = (double)kv.y;
        double kz = (double)kv.z, kw = (double)kv.w;
#pragma unroll
        for (int j = 0; j < QPT; ++j) {
          sc[j][n] = fma(qd[j][0], kx, sc[j][n]);
          sc[j][n] = fma(qd[j][1], ky, sc[j][n]);
          sc[j][n] = fma(qd[j][2], kz, sc[j][n]);
          sc[j][n] = fma(qd[j][3], kw, sc[j][n]);
        }
      }
    }
  }

  // Stable top-4: 4 passes of strictly-greater argmax over unpicked entries.
  // `-inf` for masked blocks reproduces jax.lax.top_k's ascending-index fill
  // when fewer than 4 valid blocks exist.
#pragma unroll
  for (int j = 0; j < QPT; ++j) {
    int sq = s_base + t + j * 256;
    int qb = sq >> 9;                   // query block index
    unsigned picked = 0;
    int res[4];
#pragma unroll
    for (int p = 0; p < 4; ++p) {
      int bi = -1;
      double bv = 0.0;
#pragma unroll
      for (int n = 0; n < NB; ++n) {
        if (!((picked >> n) & 1u)) {
          double val = (n <= qb) ? sc[j][n] : -INFINITY;
          if (bi < 0 || val > bv) { bi = n; bv = val; }
        }
      }
      picked |= 1u << bi;
      res[p] = bi;
    }
    int4 o = make_int4(res[0], res[1], res[2], res[3]);
    *(int4*)(out + (size_t)(base + t + j * 256) * 4) = o;
  }
}

// ---------------------------------------------------------------------------
// Kernel 3: query_block_indices[s] = s // BLOCK_SIZE
// ---------------------------------------------------------------------------
__global__ __launch_bounds__(256) void qbi_kernel(int* __restrict__ out2) {
  int s = blockIdx.x * 256 + threadIdx.x;
  if (s < SEQ) out2[s] = s >> 9;
}

extern "C" void kernel_launch(void* const* d_in, const int* in_sizes, int n_in,
                              void* d_out, int out_size, void* d_ws, size_t ws_size,
                              hipStream_t stream) {
  const float* q = (const float*)d_in[0];
  const float* k = (const float*)d_in[1];
  float* kmean = (float*)d_ws;                 // BH*NB*DIM floats = 512 KB
  int*   out   = (int*)d_out;

  hipLaunchKernelGGL(kmean_kernel, dim3(BH * NB), dim3(256), 0, stream, k, kmean);
  hipLaunchKernelGGL(score_topk_kernel, dim3(BH * SEQ / (256 * QPT)), dim3(256), 0, stream,
                     q, kmean, out);
  hipLaunchKernelGGL(qbi_kernel, dim3(SEQ / 256), dim3(256), 0, stream,
                     out + (size_t)BH * SEQ * 4);
}

// Round 2
// 652.323 us; speedup vs baseline: 1.1562x; 1.1562x over previous
//
#include <hip/hip_runtime.h>
#include <math.h>

// Problem constants (from reference setup_inputs): B=4,H=16,S=8192,D=128
#define BH   64      // B*H
#define SEQ  8192
#define DIM  128
#define NB   16      // num_blocks = S / BLOCK_SIZE
#define BS   512     // BLOCK_SIZE

// ---------------------------------------------------------------------------
// Kernel 1: k_mean[bh][nb][d] = mean over BS rows of k, double accumulation.
// Grid: BH*NB = 1024 blocks, 256 threads. Coalesced: wave covers 2 rows of
// 512B contiguous float4 reads per instruction.
// ---------------------------------------------------------------------------
__global__ __launch_bounds__(256) void kmean_kernel(const float* __restrict__ k,
                                                    float* __restrict__ kmean) {
  int blk = blockIdx.x;            // 0..BH*NB-1
  int bh  = blk >> 4;
  int nb  = blk & 15;
  const float4* base = (const float4*)(k + ((size_t)bh * SEQ + (size_t)nb * BS) * DIM);
  int t  = threadIdx.x;
  int c4 = t & 31;                 // column group (float4 index within row)
  int r0 = t >> 5;                 // 0..7
  double a0 = 0, a1 = 0, a2 = 0, a3 = 0;
  for (int r = r0; r < BS; r += 8) {
    float4 v = base[r * 32 + c4];
    a0 += (double)v.x; a1 += (double)v.y; a2 += (double)v.z; a3 += (double)v.w;
  }
  __shared__ double red[8][32][4];
  red[r0][c4][0] = a0; red[r0][c4][1] = a1;
  red[r0][c4][2] = a2; red[r0][c4][3] = a3;
  __syncthreads();
  if (r0 == 0) {
    double s0 = 0, s1 = 0, s2 = 0, s3 = 0;
#pragma unroll
    for (int r = 0; r < 8; ++r) {
      s0 += red[r][c4][0]; s1 += red[r][c4][1];
      s2 += red[r][c4][2]; s3 += red[r][c4][3];
    }
    const double inv = 1.0 / (double)BS;    // exact power of two
    float4 o;
    o.x = (float)(s0 * inv); o.y = (float)(s1 * inv);
    o.z = (float)(s2 * inv); o.w = (float)(s3 * inv);
    ((float4*)kmean)[((size_t)bh * NB + nb) * 32 + c4] = o;
  }
}

// ---------------------------------------------------------------------------
// Kernel 2: scores + causal mask + stable top-4, fully-coalesced q reads.
//
// Layout: wave = 8 groups x 8 sub-lanes. Group g owns query (qp + g);
// sub-lane u owns d-slices {u, u+8, u+16, u+24} (float4 units). Per load
// instruction each group reads a contiguous 128 B chunk -> every cache
// line fully utilized (fixes the 4x over-fetch of the row-per-thread
// layout). Partial dots in fp64, 3-step shfl_xor butterfly within the
// 8-lane group, lane u==0 does stable top-4 and writes int4 (8 groups ->
// 128 B contiguous store per wave).
//
// Grid: 1024 blocks x 256 thr; block = 4 waves = 512 consecutive queries
// (same bh), 16 passes of 8 queries per wave.
// ---------------------------------------------------------------------------
__global__ __launch_bounds__(256) void score_topk_kernel(const float* __restrict__ q,
                                                         const float* __restrict__ kmean,
                                                         int* __restrict__ out) {
  __shared__ float4 kk[NB * 32];        // 16 rows x 128 floats = 8 KB
  int t      = threadIdx.x;
  int qstart = blockIdx.x * 512;        // global query index (bh*SEQ + s)
  int bh     = qstart >> 13;

  const float4* ksrc = (const float4*)(kmean + (size_t)bh * NB * DIM);
  for (int i = t; i < NB * 32; i += 256) kk[i] = ksrc[i];
  __syncthreads();

  int wave = t >> 6;
  int lane = t & 63;
  int g    = lane >> 3;                 // query group within wave (0..7)
  int u    = lane & 7;                  // d-slice sub-lane (0..7)
  int qw   = qstart + wave * 128;       // this wave's first query

  for (int p = 0; p < 16; ++p) {
    int qp = qw + p * 8;                // first query of this pass's 8-group
    int s  = qp & (SEQ - 1);
    int qb = s >> 9;                    // query block; uniform across the 8-group

    const float4* qrow = (const float4*)(q + ((size_t)qp + g) * DIM);
    float4 qv0 = qrow[u];
    float4 qv1 = qrow[u + 8];
    float4 qv2 = qrow[u + 16];
    float4 qv3 = qrow[u + 24];

    double ps[NB];
#pragma unroll
    for (int n = 0; n < NB; ++n) ps[n] = 0.0;

#pragma unroll
    for (int n = 0; n < NB; ++n) {
      if (n <= qb) {                    // wave-uniform causal skip (~47% saved)
        float4 k0 = kk[n * 32 + u];
        float4 k1 = kk[n * 32 + u + 8];
        float4 k2 = kk[n * 32 + u + 16];
        float4 k3 = kk[n * 32 + u + 24];
        double a = 0.0;
        a = fma((double)qv0.x, (double)k0.x, a);
        a = fma((double)qv0.y, (double)k0.y, a);
        a = fma((double)qv0.z, (double)k0.z, a);
        a = fma((double)qv0.w, (double)k0.w, a);
        a = fma((double)qv1.x, (double)k1.x, a);
        a = fma((double)qv1.y, (double)k1.y, a);
        a = fma((double)qv1.z, (double)k1.z, a);
        a = fma((double)qv1.w, (double)k1.w, a);
        a = fma((double)qv2.x, (double)k2.x, a);
        a = fma((double)qv2.y, (double)k2.y, a);
        a = fma((double)qv2.z, (double)k2.z, a);
        a = fma((double)qv2.w, (double)k2.w, a);
        a = fma((double)qv3.x, (double)k3.x, a);
        a = fma((double)qv3.y, (double)k3.y, a);
        a = fma((double)qv3.z, (double)k3.z, a);
        a = fma((double)qv3.w, (double)k3.w, a);
        ps[n] = a;
      }
    }

    // Butterfly reduce over the 8 sub-lanes (xor 1,2,4): all lanes end with
    // the full score for their group's query.
#pragma unroll
    for (int n = 0; n < NB; ++n) {
      if (n <= qb) {
        double v = ps[n];
        v += __shfl_xor(v, 1, 64);
        v += __shfl_xor(v, 2, 64);
        v += __shfl_xor(v, 4, 64);
        ps[n] = v;
      }
    }

    // Stable top-4: 4 passes of strictly-greater argmax over unpicked
    // entries; -inf for masked blocks reproduces jax.lax.top_k ordering.
    unsigned picked = 0;
    int res[4];
#pragma unroll
    for (int pp = 0; pp < 4; ++pp) {
      int bi = -1;
      double bv = 0.0;
#pragma unroll
      for (int n = 0; n < NB; ++n) {
        if (!((picked >> n) & 1u)) {
          double val = (n <= qb) ? ps[n] : -INFINITY;
          if (bi < 0 || val > bv) { bi = n; bv = val; }
        }
      }
      picked |= 1u << bi;
      res[pp] = bi;
    }
    if (u == 0) {
      *(int4*)(out + ((size_t)qp + g) * 4) = make_int4(res[0], res[1], res[2], res[3]);
    }
  }
}

// ---------------------------------------------------------------------------
// Kernel 3: query_block_indices[s] = s // BLOCK_SIZE
// ---------------------------------------------------------------------------
__global__ __launch_bounds__(256) void qbi_kernel(int* __restrict__ out2) {
  int s = blockIdx.x * 256 + threadIdx.x;
  if (s < SEQ) out2[s] = s >> 9;
}

extern "C" void kernel_launch(void* const* d_in, const int* in_sizes, int n_in,
                              void* d_out, int out_size, void* d_ws, size_t ws_size,
                              hipStream_t stream) {
  const float* q = (const float*)d_in[0];
  const float* k = (const float*)d_in[1];
  float* kmean = (float*)d_ws;                 // BH*NB*DIM floats = 512 KB
  int*   out   = (int*)d_out;

  hipLaunchKernelGGL(kmean_kernel, dim3(BH * NB), dim3(256), 0, stream, k, kmean);
  hipLaunchKernelGGL(score_topk_kernel, dim3(BH * SEQ / 512), dim3(256), 0, stream,
                     q, kmean, out);
  hipLaunchKernelGGL(qbi_kernel, dim3(SEQ / 256), dim3(256), 0, stream,
                     out + (size_t)BH * SEQ * 4);
}